// Round 12
// baseline (839.364 us; speedup 1.0000x reference)
//
#include <hip/hip_runtime.h>
#include <hip/hip_bf16.h>

// GCN layer: out = (D^-1/2 A D^-1/2 X) W^T + b
// Round 22: STRUCTURAL PIVOT for the aggregation. Every register-gather
// schedule (R10/13/16/18/19/21) landed 49-62us: per-destination scalar-
// broadcast gather is latency/VALU-plateaued. Replace ELL+gather entirely:
//   k_agg: one block/bin, float agg[256][128] = 128KB LDS (m201-proven
//     size). 16 waves scan the bin's pairs edge-parallel; per edge the wave
//     reads the neighbor xs row ONCE (64 coalesced dwords, uniform base),
//     scales by dis[col] (readlane), and ds_add_f32 (fire-and-forget LDS
//     atomic) into the destination row. Then in-place f32->bf16 repack
//     (linear b64 reads, bank-optimal; agg reused as the ROWSTRIDE-136
//     smem layout) + VERIFIED MFMA epilogue (2 passes x 4 groups x 4-wave
//     unit). Eliminates: ell array (6.4MB w+r), degc, k_ell stage, and all
//     per-row gather latency windows.
//   k_bin: R20 verbatim (binning only).
//   k_deg: pairs scan -> cnt -> dis, with W/xs casts overlapped in-grid.
//
// ws: gbin 25KB | pairs 5.6MB | dis[nrows] 200KB | xs 12.85MB | wb 32KB
//     ~= 18.7 MB

typedef short v8s __attribute__((ext_vector_type(8)));
typedef float v4f __attribute__((ext_vector_type(4)));

#define NSHARD 32     // reservation shards per bin (depth ~391/32 ~= 12)
#define SUBCAP 224    // per (bin,shard) ~ Poisson(131); +8 sigma. Guarded.
#define ROWSTRIDE 136 // 128 bf16 + 8 pad shorts; 272 B rows (16B-aligned)
#define EPB 2048      // edges per binning block (8 per thread)
#define AGG_S 128     // f32 row stride in agg: 256*128*4 = 131072 B LDS

static __device__ __forceinline__ unsigned int f2bf(float f) {
    __hip_bfloat16 h = __float2bfloat16(f);  // RNE
    return (unsigned int)__builtin_bit_cast(unsigned short, h);
}

// k_bin: binning only (R20 verbatim). 2048 edges/block; LDS hist -> sharded
// reservation (overlapped with local-offset pass) -> packed scatter.
__global__ __launch_bounds__(256) void k_bin(
    const int* __restrict__ idx, int* __restrict__ gbin,
    unsigned int* __restrict__ pairs, int E, int nbins) {
    const int b = blockIdx.x;
    const int t = threadIdx.x;
    __shared__ int hist[256];
    __shared__ int hist2[256];
    __shared__ int base[256];
    hist[t] = 0;
    hist2[t] = 0;
    __syncthreads();

    int e0 = b * EPB + t * 8;
    int nv = E - e0;
    nv = nv > 8 ? 8 : (nv < 0 ? 0 : nv);
    int rows[8], cols[8];
    if (nv == 8) {
        int4 a0 = *(const int4*)&idx[e0];
        int4 a1 = *(const int4*)&idx[e0 + 4];
        int4 c0 = *(const int4*)&idx[E + e0];
        int4 c1 = *(const int4*)&idx[E + e0 + 4];
        rows[0] = a0.x; rows[1] = a0.y; rows[2] = a0.z; rows[3] = a0.w;
        rows[4] = a1.x; rows[5] = a1.y; rows[6] = a1.z; rows[7] = a1.w;
        cols[0] = c0.x; cols[1] = c0.y; cols[2] = c0.z; cols[3] = c0.w;
        cols[4] = c1.x; cols[5] = c1.y; cols[6] = c1.z; cols[7] = c1.w;
    } else {
        for (int k = 0; k < 8; ++k) {
            rows[k] = (k < nv) ? idx[e0 + k] : 0;
            cols[k] = (k < nv) ? idx[E + e0 + k] : 0;
        }
    }
#pragma unroll
    for (int k = 0; k < 8; ++k)
        if (k < nv) atomicAdd(&hist[rows[k] >> 8], 1);
    __syncthreads();
    const int shard = b & (NSHARD - 1);
    if (t < nbins)  // ~12-deep contention; returns while hist2 pass runs
        base[t] = atomicAdd(&gbin[t * NSHARD + shard], hist[t]);
    int loc[8];
#pragma unroll
    for (int k = 0; k < 8; ++k)
        loc[k] = (k < nv) ? atomicAdd(&hist2[rows[k] >> 8], 1) : 0;
    __syncthreads();
#pragma unroll
    for (int k = 0; k < 8; ++k) {
        if (k < nv) {
            int bin = rows[k] >> 8;
            int pos = base[bin] + loc[k];
            if (pos < SUBCAP)
                pairs[((size_t)bin * NSHARD + shard) * SUBCAP + pos] =
                    (unsigned)(((rows[k] & 255) << 16) | cols[k]);
        }
    }
}

// k_deg: mixed grid, 1024 thr.
//   [0,nbins): scan own bin's 32 sub-regions (32-lane group each), LDS cnt,
//     dis[r] = rsqrt(deg) (0 for deg==0 / rows >= N).
//   [nbins,nbins+4): W cast. [nbins+4,...): xs cast (4096 dwords each).
__global__ __launch_bounds__(1024) void k_deg(
    const unsigned int* __restrict__ pairs, const int* __restrict__ gbin,
    float* __restrict__ dis, const float4* __restrict__ w4,
    ushort4* __restrict__ wb4, const float2* __restrict__ x2,
    unsigned int* __restrict__ xs32, int N, int nbins) {
    const int t = threadIdx.x;
    int b = blockIdx.x;
    if (b >= nbins) {
        b -= nbins;
        if (b < 4) {  // W cast: 4 blocks x 1024 thr = 4096 float4s
            int i = b * 1024 + t;
            float4 v = w4[i];
            ushort4 o;
            o.x = (unsigned short)f2bf(v.x);
            o.y = (unsigned short)f2bf(v.y);
            o.z = (unsigned short)f2bf(v.z);
            o.w = (unsigned short)f2bf(v.w);
            wb4[i] = o;
            return;
        }
        b -= 4;
        int base = b * 4096;  // xs cast: unscaled bf16, rows >= N -> zeros
#pragma unroll
        for (int it = 0; it < 4; ++it) {
            int i = base + it * 1024 + t;
            int lr = i >> 6;
            unsigned ov = 0u;
            if (lr < N) {
                float2 v = x2[i];
                ov = f2bf(v.x) | (f2bf(v.y) << 16);
            }
            xs32[i] = ov;
        }
        return;
    }
    __shared__ int cnt[256];
    if (t < 256) cnt[t] = 0;
    __syncthreads();
    {
        const int g = t >> 5, l32 = t & 31;  // group g owns sub-region g
        int m = gbin[b * NSHARD + g];
        m = m > SUBCAP ? SUBCAP : m;
        size_t pb = ((size_t)b * NSHARD + g) * SUBCAP;
        for (int i = l32; i < m; i += 32)
            atomicAdd(&cnt[pairs[pb + i] >> 16], 1);
    }
    __syncthreads();
    if (t < 256) {
        int r = b * 256 + t;
        int d = cnt[t];
        dis[r] = (r < N && d > 0) ? rsqrtf((float)d) : 0.f;
    }
}

// k_agg: one block/bin, 1024 thr (16 waves), 128KB LDS f32 accumulator.
// Phase 1: zero. Phase 2: edge-parallel scan; per edge one coalesced xs-row
// read + 2 ds_add_f32 per lane (fire-and-forget). Phase 3: in-place
// f32->bf16 repack (regs across a barrier) into ROWSTRIDE-136 layout.
// Phase 4: verified MFMA epilogue, 2 passes x 4 groups x 4-wave unit.
__global__ __launch_bounds__(1024) void k_agg(
    const unsigned int* __restrict__ pairs, const int* __restrict__ gbin,
    const float* __restrict__ dis, const unsigned int* __restrict__ xs32,
    const v8s* __restrict__ Wb8, const float* __restrict__ bias,
    float* __restrict__ out, int N) {
    __shared__ __align__(16) float agg[256 * AGG_S];  // 131072 B
    const int bin = blockIdx.x;
    const int t = threadIdx.x;
    const int wv = t >> 6, lane = t & 63;

    {  // zero: 8192 float4 / 1024 thr = 8 each
        float4 z = {0.f, 0.f, 0.f, 0.f};
        float4* a4 = (float4*)agg;
#pragma unroll
        for (int i = 0; i < 8; ++i) a4[t + i * 1024] = z;
    }
    __syncthreads();

    // accumulate: wave wv scans sub-regions wv and wv+16
    for (int sh = wv; sh < NSHARD; sh += 16) {
        int m = gbin[bin * NSHARD + sh];
        m = m > SUBCAP ? SUBCAP : m;
        size_t pb = ((size_t)bin * NSHARD + sh) * SUBCAP;
        for (int base = 0; base < m; base += 64) {
            int i = base + lane;
            unsigned pv = (i < m) ? pairs[pb + i] : 0u;
            float dvl = (i < m) ? dis[pv & 0xFFFF] : 0.f;  // tail -> scale 0
            int dvb = __builtin_bit_cast(int, dvl);
            int jmax = m - base;
            jmax = jmax > 64 ? 64 : jmax;
            for (int j0 = 0; j0 < jmax; j0 += 16) {  // 16-edge batches
                unsigned uu[16];
                float sc[16];
                int ll[16];
#pragma unroll
                for (int u = 0; u < 16; ++u) {
                    int p = __builtin_amdgcn_readlane((int)pv, j0 + u);
                    sc[u] = __builtin_bit_cast(
                        float, __builtin_amdgcn_readlane(dvb, j0 + u));
                    ll[u] = (p >> 16) & 255;
                    int col = p & 0xFFFF;
                    uu[u] = xs32[(size_t)col * 64 + lane];  // uniform base
                }
#pragma unroll
                for (int u = 0; u < 16; ++u) {
                    float* rowp = &agg[ll[u] * AGG_S + 2 * lane];
                    atomicAdd(&rowp[0],
                              sc[u] * __builtin_bit_cast(float, uu[u] << 16));
                    atomicAdd(&rowp[1], sc[u] * __builtin_bit_cast(
                                            float, uu[u] & 0xFFFF0000u));
                }
            }
        }
    }
    __syncthreads();

    // repack: read 16 float2 each (linear, bank-optimal), scale by dis[row],
    // cvt+pack to regs; barrier; write as bf16 ROWSTRIDE-136 rows in-place.
    unsigned pk[16];
#pragma unroll
    for (int it = 0; it < 16; ++it) {
        int j = t + 1024 * it;  // float2 index; 64 float2 per row
        int r = j >> 6, p = j & 63;
        float2 v = *(const float2*)&agg[r * AGG_S + 2 * p];
        float s = dis[bin * 256 + r];  // 0 for rows >= N
        pk[it] = f2bf(v.x * s) | (f2bf(v.y * s) << 16);
    }
    __syncthreads();  // all f32 reads done before overwrite
    {
        unsigned short* sm = (unsigned short*)agg;
#pragma unroll
        for (int it = 0; it < 16; ++it) {
            int j = t + 1024 * it;
            int r = j >> 6, p = j & 63;
            *(unsigned int*)&sm[r * ROWSTRIDE + 2 * p] = pk[it];
        }
    }
    __syncthreads();

    // MFMA (verified layout: A m=lane&15 k=quad*8+i; B row-major W bf16;
    // C/D col=lane&15 row=quad*4+reg). 16 waves = 2 passes x 4 groups x
    // {rows (w4&1)*16, cols (w4>>1)*64} 4-wave unit.
    {
        const unsigned short* sm = (const unsigned short*)agg;
        int g = wv >> 2, w4 = wv & 3;
        int quad = lane >> 4, m16 = lane & 15;
#pragma unroll
        for (int pass = 0; pass < 2; ++pass) {
            int lrow = pass * 128 + g * 32 + (w4 & 1) * 16 + m16;
            v8s afrag[4];
#pragma unroll
            for (int kk = 0; kk < 4; ++kk)
                afrag[kk] =
                    *(const v8s*)&sm[lrow * ROWSTRIDE + kk * 32 + quad * 8];
            int rbase = bin * 256 + pass * 128 + g * 32 + (w4 & 1) * 16 + quad * 4;
            int jbase = (w4 >> 1) * 64;
#pragma unroll
            for (int jt = 0; jt < 4; ++jt) {
                int jcol = jbase + jt * 16 + m16;
                v4f acc = {0.f, 0.f, 0.f, 0.f};
#pragma unroll
                for (int kk = 0; kk < 4; ++kk) {
                    v8s bfrag = Wb8[jcol * 16 + kk * 4 + quad];
                    acc = __builtin_amdgcn_mfma_f32_16x16x32_bf16(afrag[kk],
                                                                  bfrag, acc,
                                                                  0, 0, 0);
                }
                float bj = bias[jcol];
#pragma unroll
                for (int r = 0; r < 4; ++r) {
                    int row = rbase + r;
                    if (row < N) out[(size_t)row * 128 + jcol] = acc[r] + bj;
                }
            }
        }
    }
}

extern "C" void kernel_launch(void* const* d_in, const int* in_sizes, int n_in,
                              void* d_out, int out_size, void* d_ws, size_t ws_size,
                              hipStream_t stream) {
    const float* x = (const float*)d_in[0];
    const int* idx = (const int*)d_in[1];
    const float* W = (const float*)d_in[2];
    const float* b = (const float*)d_in[3];
    float* out = (float*)d_out;

    const int N = in_sizes[0] / 128;    // 50000
    const int E = in_sizes[1] / 2;      // 800000
    const int nbins = (N + 255) / 256;  // 196 (<= 256 required)
    const int nrows = nbins * 256;      // 50176
    const int ncast = nrows / 64;       // 784 xs-cast blocks x 4096 dwords

    char* p = (char*)d_ws;
    auto alloc = [&](size_t bytes) {
        char* r = p;
        p += (bytes + 63) & ~(size_t)63;
        return r;
    };
    int* gbin = (int*)alloc((size_t)nbins * NSHARD * 4);  // 25 KB
    unsigned int* pairs =
        (unsigned int*)alloc((size_t)nbins * NSHARD * SUBCAP * 4);  // 5.6 MB
    float* dis = (float*)alloc((size_t)nrows * 4);                  // 200 KB
    unsigned int* xs = (unsigned int*)alloc((size_t)nrows * 128 * 2);  // 12.85 MB
    ushort4* wb = (ushort4*)alloc(128 * 128 * 2);                      // 32 KB

    hipMemsetAsync(gbin, 0, (size_t)nbins * NSHARD * sizeof(int), stream);

    const int bblocks = (E + EPB - 1) / EPB;  // 391, binning only
    k_bin<<<bblocks, 256, 0, stream>>>(idx, gbin, pairs, E, nbins);
    // 196 deg blocks + 4 W-cast + 784 xs-cast, casts overlap the scan
    k_deg<<<nbins + 4 + ncast, 1024, 0, stream>>>(pairs, gbin, dis,
                                                  (const float4*)W, wb,
                                                  (const float2*)x, xs, N, nbins);
    k_agg<<<nbins, 1024, 0, stream>>>(pairs, gbin, dis, xs, (const v8s*)wb, b,
                                      out, N);
}

// Round 13
// 138.859 us; speedup vs baseline: 6.0447x; 6.0447x over previous
//
#include <hip/hip_runtime.h>
#include <hip/hip_bf16.h>

// GCN layer: out = (D^-1/2 A D^-1/2 X) W^T + b
// Round 23 = R20 (144.5us verified best) with ONE change: k_fused 256->512
// threads (8 waves), 4 rows/wave. R22 falsified LDS-atomic accumulation
// (750us: LDS f32 RMW atomics serialize the DS pipe). The gather is
// L2-miss-latency-bound (VALUBusy 27%, occ 40%, FETCH 76MB on ~205MB
// gather): double the waves/SIMD to double outstanding loads, halve the
// per-wave serial row chain. MFMA epilogue re-derived for 8 waves: 2 groups
// x 4 waves, group g owns rows [g*16,g*16+16), wave-in-group owns a 32-col
// strip (same verified fragment math, different wave->tile assignment).
//   k_bin: R20 verbatim (binning only).
//   k_ell: R20 verbatim (ELL build + W/xs casts overlapped).
//
// ws: gbin[196*32] 25KB | pairs[196*32*224 u32] 5.6MB | dis[nrows f32]
//     200KB | degc[N] 50KB | ell[nrows*64 u16] 6.42MB | xs 12.85MB |
//     wb 32KB  ~= 25.2 MB (< 26 MB proven)

typedef short v8s __attribute__((ext_vector_type(8)));
typedef float v4f __attribute__((ext_vector_type(4)));

#define ELLCAP 64     // deg ~ Poisson(16); P(deg>64) ~ 1e-19/node. Guarded.
#define NSHARD 32     // reservation shards per bin (depth ~391/32 ~= 12)
#define SUBCAP 224    // per (bin,shard) ~ Poisson(131); +8 sigma. Guarded.
#define ROWSTRIDE 136 // 128 bf16 + 8 pad shorts; 272 B rows (16B-aligned)
#define EPB 2048      // edges per binning block (8 per thread, R18-proven)

static __device__ __forceinline__ unsigned int f2bf(float f) {
    __hip_bfloat16 h = __float2bfloat16(f);  // RNE
    return (unsigned int)__builtin_bit_cast(unsigned short, h);
}

// k_bin: binning only. 2048 edges/block; LDS hist -> sharded reservation
// (overlapped with LDS local-offset pass) -> packed (localrow,col) scatter.
__global__ __launch_bounds__(256) void k_bin(
    const int* __restrict__ idx, int* __restrict__ gbin,
    unsigned int* __restrict__ pairs, int E, int nbins) {
    const int b = blockIdx.x;
    const int t = threadIdx.x;
    __shared__ int hist[256];
    __shared__ int hist2[256];
    __shared__ int base[256];
    hist[t] = 0;
    hist2[t] = 0;
    __syncthreads();

    int e0 = b * EPB + t * 8;
    int nv = E - e0;
    nv = nv > 8 ? 8 : (nv < 0 ? 0 : nv);
    int rows[8], cols[8];
    if (nv == 8) {
        int4 a0 = *(const int4*)&idx[e0];
        int4 a1 = *(const int4*)&idx[e0 + 4];
        int4 c0 = *(const int4*)&idx[E + e0];
        int4 c1 = *(const int4*)&idx[E + e0 + 4];
        rows[0] = a0.x; rows[1] = a0.y; rows[2] = a0.z; rows[3] = a0.w;
        rows[4] = a1.x; rows[5] = a1.y; rows[6] = a1.z; rows[7] = a1.w;
        cols[0] = c0.x; cols[1] = c0.y; cols[2] = c0.z; cols[3] = c0.w;
        cols[4] = c1.x; cols[5] = c1.y; cols[6] = c1.z; cols[7] = c1.w;
    } else {
        for (int k = 0; k < 8; ++k) {
            rows[k] = (k < nv) ? idx[e0 + k] : 0;
            cols[k] = (k < nv) ? idx[E + e0 + k] : 0;
        }
    }
#pragma unroll
    for (int k = 0; k < 8; ++k)
        if (k < nv) atomicAdd(&hist[rows[k] >> 8], 1);
    __syncthreads();
    const int shard = b & (NSHARD - 1);
    if (t < nbins)  // ~12-deep contention; returns while hist2 pass runs
        base[t] = atomicAdd(&gbin[t * NSHARD + shard], hist[t]);
    // overlap: per-edge local offsets via LDS while reservations in flight
    int loc[8];
#pragma unroll
    for (int k = 0; k < 8; ++k)
        loc[k] = (k < nv) ? atomicAdd(&hist2[rows[k] >> 8], 1) : 0;
    __syncthreads();
#pragma unroll
    for (int k = 0; k < 8; ++k) {
        if (k < nv) {
            int bin = rows[k] >> 8;
            int pos = base[bin] + loc[k];
            if (pos < SUBCAP)
                pairs[((size_t)bin * NSHARD + shard) * SUBCAP + pos] =
                    (unsigned)(((rows[k] & 255) << 16) | cols[k]);
        }
    }
}

// k_ell: mixed grid, 1024 thr.
//   blocks [0,nbins): ELL build: 32 groups x 32 lanes scan sub-regions,
//     LDS ELL, 32KB coalesced dump, dis/degc.
//   blocks [nbins,nbins+4): W cast. [nbins+4,...): xs cast (4096 dwords).
__global__ __launch_bounds__(1024) void k_ell(
    const unsigned int* __restrict__ pairs, const int* __restrict__ gbin,
    unsigned short* __restrict__ ell, unsigned char* __restrict__ degc,
    float* __restrict__ dis, const float4* __restrict__ w4,
    ushort4* __restrict__ wb4, const float2* __restrict__ x2,
    unsigned int* __restrict__ xs32, int N, int nbins) {
    const int t = threadIdx.x;
    int b = blockIdx.x;
    if (b >= nbins) {
        b -= nbins;
        if (b < 4) {  // W cast: 4 blocks x 1024 thr = 4096 float4s
            int i = b * 1024 + t;
            float4 v = w4[i];
            ushort4 o;
            o.x = (unsigned short)f2bf(v.x);
            o.y = (unsigned short)f2bf(v.y);
            o.z = (unsigned short)f2bf(v.z);
            o.w = (unsigned short)f2bf(v.w);
            wb4[i] = o;
            return;
        }
        b -= 4;
        // xs cast: 4096 dwords (64 rows) per block, unscaled bf16
        int base = b * 4096;
#pragma unroll
        for (int it = 0; it < 4; ++it) {
            int i = base + it * 1024 + t;
            int lr = i >> 6;  // global row
            unsigned ov = 0u;
            if (lr < N) {
                float2 v = x2[i];
                ov = f2bf(v.x) | (f2bf(v.y) << 16);
            }
            xs32[i] = ov;  // rows >= N (incl. pad row N) -> zeros
        }
        return;
    }

    __shared__ __align__(16) unsigned short lell[256 * ELLCAP];  // 32 KB
    __shared__ int cnt[256];
    const int bin = b;
    if (t < 256) cnt[t] = 0;
    __syncthreads();

    {
        const int g = t >> 5, l32 = t & 31;  // group g owns sub-region g
        int m = gbin[bin * NSHARD + g];
        m = m > SUBCAP ? SUBCAP : m;
        size_t pb = ((size_t)bin * NSHARD + g) * SUBCAP;
        for (int i = l32; i < m; i += 32) {
            unsigned pv = pairs[pb + i];
            int la = pv >> 16;
            int slot = atomicAdd(&cnt[la], 1);
            if (slot < ELLCAP)
                lell[la * ELLCAP + slot] = (unsigned short)(pv & 0xFFFF);
        }
    }
    __syncthreads();

    if (t < 256) {
        int r = bin * 256 + t;
        int d = cnt[t];
        if (r < N) {
            dis[r] = (d > 0) ? rsqrtf((float)d) : 0.f;
            degc[r] = (unsigned char)(d > ELLCAP ? ELLCAP : d);
        } else {
            dis[r] = 0.f;  // incl. pad row N
        }
    }

    // coalesced ELL dump: 32 KB = 8192 dwords into ell rows [bin*256,+256)
    {
        unsigned int* gell = (unsigned int*)(ell + (size_t)bin * 256 * ELLCAP);
        const unsigned int* sell = (const unsigned int*)lell;
        for (int i = t; i < 8192; i += 1024) gell[i] = sell[i];
    }
}

// k_fused: 512 thr (8 waves), 32 rows/block, 4 rows/wave. Global ELL, no
// build phase. Prologue prefetch (4 rows of degc + ell + dis[c] independent
// loads), 16-wide readlane batches, 8-wave MFMA epilogue (2 groups x 4
// waves; group g = rows [g*16,+16), wave-in-group = 32-col strip).
__global__ __launch_bounds__(512) void k_fused(
    const unsigned short* __restrict__ ell, const unsigned char* __restrict__ degc,
    const float* __restrict__ dis, const unsigned int* __restrict__ xs32,
    const v8s* __restrict__ Wb8, const float* __restrict__ bias,
    float* __restrict__ out, int N) {
    __shared__ __align__(16) unsigned short smem[32 * ROWSTRIDE];
    const int nb0 = blockIdx.x * 32;
    const int wv = threadIdx.x >> 6, lane = threadIdx.x & 63;
    const int rowbase = nb0 + wv * 4;

    // prologue: independent loads for all 4 rows (no serial chains)
    int d4[4], c4[4];
    float dv4[4];
#pragma unroll
    for (int i = 0; i < 4; ++i) {
        int n = rowbase + i;
        int d = (n < N) ? degc[n] : 0;
        d4[i] = __builtin_amdgcn_readfirstlane(d);
        int cl = (n < N) ? ell[(size_t)n * ELLCAP + lane] : 0;
        c4[i] = (lane < d4[i]) ? cl : N;  // pad -> zero row, dis=0
    }
#pragma unroll
    for (int i = 0; i < 4; ++i) dv4[i] = dis[c4[i]];  // 4 independent gathers

#pragma unroll
    for (int i = 0; i < 4; ++i) {
        int n = rowbase + i;
        float acc0 = 0.f, acc1 = 0.f;
        int d = d4[i];
        int c = c4[i];
        int dcb = __builtin_bit_cast(int, dv4[i]);
        for (int j = 0; j < d; j += 16) {  // j in {0,16,32,48}
            int cc[16];
#pragma unroll
            for (int u = 0; u < 16; ++u)
                cc[u] = __builtin_amdgcn_readlane(c, j + u);
            unsigned uu[16];
#pragma unroll
            for (int u = 0; u < 16; ++u)
                uu[u] = xs32[(size_t)cc[u] * 64 + lane];
            float sc[16];
#pragma unroll
            for (int u = 0; u < 16; ++u)
                sc[u] = __builtin_bit_cast(float,
                                           __builtin_amdgcn_readlane(dcb, j + u));
#pragma unroll
            for (int u = 0; u < 16; ++u) {
                acc0 = fmaf(sc[u], __builtin_bit_cast(float, uu[u] << 16), acc0);
                acc1 = fmaf(sc[u],
                            __builtin_bit_cast(float, uu[u] & 0xFFFF0000u), acc1);
            }
        }
        float s = dis[n];  // rows >= N read dis=0 (sized nrows)
        acc0 *= s;
        acc1 *= s;
        unsigned pack = f2bf(acc0) | (f2bf(acc1) << 16);
        *(unsigned int*)&smem[(size_t)(wv * 4 + i) * ROWSTRIDE + lane * 2] = pack;
    }
    __syncthreads();

    // MFMA 8-wave epilogue (verified fragment math: A m=lane&15 k=quad*8+i;
    // B row-major W bf16; C/D col=lane&15 row=quad*4+reg). Group g=wv>>2
    // owns rows [g*16,g*16+16); wave-in-group w4 owns cols [w4*32,+32).
    {
        int g = wv >> 2, w4 = wv & 3;
        int quad = lane >> 4, m16 = lane & 15;
        int lrow = g * 16 + m16;
        v8s afrag[4];
#pragma unroll
        for (int kk = 0; kk < 4; ++kk)
            afrag[kk] = *(const v8s*)&smem[lrow * ROWSTRIDE + kk * 32 + quad * 8];
        int rbase = nb0 + g * 16 + quad * 4;
        int jbase = w4 * 32;
#pragma unroll
        for (int jt = 0; jt < 2; ++jt) {
            int jcol = jbase + jt * 16 + m16;
            v4f acc = {0.f, 0.f, 0.f, 0.f};
#pragma unroll
            for (int kk = 0; kk < 4; ++kk) {
                v8s bfrag = Wb8[jcol * 16 + kk * 4 + quad];
                acc = __builtin_amdgcn_mfma_f32_16x16x32_bf16(afrag[kk], bfrag,
                                                              acc, 0, 0, 0);
            }
            float bj = bias[jcol];
#pragma unroll
            for (int r = 0; r < 4; ++r) {
                int row = rbase + r;
                if (row < N) out[(size_t)row * 128 + jcol] = acc[r] + bj;
            }
        }
    }
}

extern "C" void kernel_launch(void* const* d_in, const int* in_sizes, int n_in,
                              void* d_out, int out_size, void* d_ws, size_t ws_size,
                              hipStream_t stream) {
    const float* x = (const float*)d_in[0];
    const int* idx = (const int*)d_in[1];
    const float* W = (const float*)d_in[2];
    const float* b = (const float*)d_in[3];
    float* out = (float*)d_out;

    const int N = in_sizes[0] / 128;    // 50000
    const int E = in_sizes[1] / 2;      // 800000
    const int nbins = (N + 255) / 256;  // 196 (<= 256 required)
    const int nrows = nbins * 256;      // 50176 (covers pad row N)
    const int ncast = nrows / 64;       // 784 xs-cast blocks x 4096 dwords

    char* p = (char*)d_ws;
    auto alloc = [&](size_t bytes) {
        char* r = p;
        p += (bytes + 63) & ~(size_t)63;
        return r;
    };
    int* gbin = (int*)alloc((size_t)nbins * NSHARD * 4);  // 25 KB
    unsigned int* pairs =
        (unsigned int*)alloc((size_t)nbins * NSHARD * SUBCAP * 4);  // 5.6 MB
    float* dis = (float*)alloc((size_t)nrows * 4);                  // 200 KB
    unsigned char* degc = (unsigned char*)alloc((size_t)N);         // 50 KB
    unsigned short* ell =
        (unsigned short*)alloc((size_t)nrows * ELLCAP * 2);  // 6.42 MB (nrows!)
    unsigned int* xs = (unsigned int*)alloc((size_t)nrows * 128 * 2);  // 12.85 MB
    ushort4* wb = (ushort4*)alloc(128 * 128 * 2);                      // 32 KB

    hipMemsetAsync(gbin, 0, (size_t)nbins * NSHARD * sizeof(int), stream);

    const int bblocks = (E + EPB - 1) / EPB;  // 391, binning only
    k_bin<<<bblocks, 256, 0, stream>>>(idx, gbin, pairs, E, nbins);
    // 196 ELL + 4 W-cast + 784 xs-cast blocks, casts overlap the pairs scan
    k_ell<<<nbins + 4 + ncast, 1024, 0, stream>>>(pairs, gbin, ell, degc, dis,
                                                  (const float4*)W, wb,
                                                  (const float2*)x, xs, N, nbins);
    k_fused<<<(N + 31) / 32, 512, 0, stream>>>(ell, degc, dis, xs,
                                               (const v8s*)wb, b, out, N);
}